// Round 4
// baseline (474.988 us; speedup 1.0000x reference)
//
#include <hip/hip_runtime.h>
#include <math.h>

#define NTOK 16384
#define HDIM 4096
#define NEXP 64
#define SPLITS 4
#define KRANGE (HDIM / SPLITS)  // 1024 K per split
#define KC 64                   // K per chunk (2 MFMA k-steps)
#define TOKTILE 64              // tokens per block (4 waves x 16)

typedef _Float16 half8 __attribute__((ext_vector_type(8)));
typedef float floatx4 __attribute__((ext_vector_type(4)));

// ---------------- W split: w' = 64*w = g1 + g2/2048 (both fp16, normal range) ----------------
__global__ __launch_bounds__(256) void wsplit_kernel(const float* __restrict__ W,
                                                     _Float16* __restrict__ g1,
                                                     _Float16* __restrict__ g2) {
  const int i = ((int)blockIdx.x * 256 + (int)threadIdx.x) * 4;
  float4 v = *(const float4*)&W[i];
  float vv[4] = {v.x, v.y, v.z, v.w};
#pragma unroll
  for (int j = 0; j < 4; ++j) {
    float w = vv[j] * 64.0f;            // scale to ~N(0,1): fp16-normal territory
    _Float16 a = (_Float16)w;           // RNE
    _Float16 b = (_Float16)((w - (float)a) * 2048.0f);  // rescaled residual (exact sub)
    g1[i + j] = a;
    g2[i + j] = b;
  }
}

// ---------------- MFMA GEMM, no LDS: A-frags from x (fp32->2xfp16 in-reg), B-frags
// straight from g1/g2 (W is natively B^T = [exp][k], L1/L2-hot 1 MB).
// logits = (1/64)*[accA + 2^-11*accB + 2^-22*accC]; accA per split fp64-combined in topk.
__global__ __launch_bounds__(256) void gemm_mfma(const float* __restrict__ x,
                                                 const _Float16* __restrict__ g1,
                                                 const _Float16* __restrict__ g2,
                                                 float* __restrict__ part) {
  const int split = (int)blockIdx.x & 3;
  const int tile = (int)blockIdx.x >> 2;
  const int kbase = split * KRANGE;
  const int lane = (int)threadIdx.x & 63;
  const int wave = (int)threadIdx.x >> 6;
  const int tok0 = tile * TOKTILE + wave * 16;  // this wave's 16-token m-tile
  const int m = lane & 15;  // A: token row; B: expert row; D: expert col
  const int q = lane >> 4;  // k-quad: frag k = q*8 + j

  const float* xrow = x + (size_t)(tok0 + m) * HDIM + kbase + q * 8;

  floatx4 accA[4], accB[4], accC[4];
#pragma unroll
  for (int nt = 0; nt < 4; ++nt) {
    accA[nt] = (floatx4){0.0f, 0.0f, 0.0f, 0.0f};
    accB[nt] = (floatx4){0.0f, 0.0f, 0.0f, 0.0f};
    accC[nt] = (floatx4){0.0f, 0.0f, 0.0f, 0.0f};
  }

  for (int c = 0; c < KRANGE / KC; ++c) {
    const int k0 = c * KC;
    // A-frags for both k-steps: load x fp32, split into (x1, x2*2048) fp16
    half8 a1[2], a2[2];
#pragma unroll
    for (int s = 0; s < 2; ++s) {
      float4 u0 = *(const float4*)(xrow + k0 + s * 32);
      float4 u1 = *(const float4*)(xrow + k0 + s * 32 + 4);
      float uv[8] = {u0.x, u0.y, u0.z, u0.w, u1.x, u1.y, u1.z, u1.w};
#pragma unroll
      for (int j = 0; j < 8; ++j) {
        _Float16 h1 = (_Float16)uv[j];                                 // RNE
        _Float16 h2 = (_Float16)((uv[j] - (float)h1) * 2048.0f);       // exact sub, scaled
        a1[s][j] = h1;
        a2[s][j] = h2;
      }
    }
#pragma unroll
    for (int nt = 0; nt < 4; ++nt) {
      const size_t wb = (size_t)(nt * 16 + m) * HDIM + kbase + k0 + q * 8;
#pragma unroll
      for (int s = 0; s < 2; ++s) {
        half8 b1 = *(const half8*)(g1 + wb + s * 32);
        half8 b2 = *(const half8*)(g2 + wb + s * 32);
        accA[nt] = __builtin_amdgcn_mfma_f32_16x16x32_f16(a1[s], b1, accA[nt], 0, 0, 0);
        accB[nt] = __builtin_amdgcn_mfma_f32_16x16x32_f16(a1[s], b2, accB[nt], 0, 0, 0);
        accB[nt] = __builtin_amdgcn_mfma_f32_16x16x32_f16(a2[s], b1, accB[nt], 0, 0, 0);
        accC[nt] = __builtin_amdgcn_mfma_f32_16x16x32_f16(a2[s], b2, accC[nt], 0, 0, 0);
      }
    }
  }

  // D layout (m89-verified): col = lane&15 (expert), row = q*4 + r (token)
#pragma unroll
  for (int nt = 0; nt < 4; ++nt) {
#pragma unroll
    for (int r = 0; r < 4; ++r) {
      const int tok = tok0 + q * 4 + r;
      const int e = nt * 16 + m;
      float corr = accB[nt][r] * 4.8828125e-4f            // 2^-11
                 + accC[nt][r] * 2.384185791015625e-7f;   // 2^-22
      part[((size_t)(split * 2 + 0) * NTOK + tok) * NEXP + e] = accA[nt][r];
      part[((size_t)(split * 2 + 1) * NTOK + tok) * NEXP + e] = corr;
    }
  }
}

// ---------------- split-reduce + top-8 + softmax + usage counts ----------------
// Wave per token, lane = expert (R2-verified butterfly). 16 tokens / 1024-thr block.
__global__ __launch_bounds__(1024) void topk_kernel(const float* __restrict__ part,
                                                    float* __restrict__ out_scores,
                                                    float* __restrict__ out_idx,
                                                    unsigned int* __restrict__ counts) {
  __shared__ unsigned int lcnt[64];
  if (threadIdx.x < 64) lcnt[threadIdx.x] = 0u;
  __syncthreads();

  const int n = (int)blockIdx.x * 16 + ((int)threadIdx.x >> 6);
  const int e = (int)threadIdx.x & 63;

  // deterministic fp64 combine of split mains + corrections, then *1/64 (w scale)
  double s = 0.0;
#pragma unroll
  for (int sp = 0; sp < SPLITS; ++sp) {
    s += (double)part[((size_t)(sp * 2 + 0) * NTOK + n) * NEXP + e];
    s += (double)part[((size_t)(sp * 2 + 1) * NTOK + n) * NEXP + e];
  }
  float live = (float)(s * 0.015625);

  float vj[8];
  int ij[8];
#pragma unroll
  for (int j = 0; j < 8; ++j) {
    float bv = live;
    int bi = e;
#pragma unroll
    for (int off = 1; off < 64; off <<= 1) {
      float ov = __shfl_xor(bv, off);
      int oi = __shfl_xor(bi, off);
      if (ov > bv || (ov == bv && oi < bi)) { bv = ov; bi = oi; }
    }
    vj[j] = bv; ij[j] = bi;            // all lanes agree
    if (e == bi) live = -INFINITY;     // winner drops out
  }

  float mx = vj[0], sum = 0.0f, sc[8];
#pragma unroll
  for (int j = 0; j < 8; ++j) { sc[j] = expf(vj[j] - mx); sum += sc[j]; }
  float inv = 1.0f / sum;

  float myscore = 0.0f; int myidx = 0;
#pragma unroll
  for (int j = 0; j < 8; ++j)
    if (e == j) { myscore = sc[j] * inv; myidx = ij[j]; }
  if (e < 8) {
    out_scores[(size_t)n * 8 + e] = myscore;
    out_idx[(size_t)n * 8 + e] = (float)myidx;
    atomicAdd(&lcnt[myidx], 1u);
  }
  __syncthreads();
  if (threadIdx.x < 64) atomicAdd(&counts[threadIdx.x], lcnt[threadIdx.x]);
}

// ---------------- load-balance loss ----------------
__global__ __launch_bounds__(64) void loss_kernel(const unsigned int* __restrict__ counts,
                                                  float* __restrict__ out_loss) {
  const int e = (int)threadIdx.x;
  double d = (double)counts[e] / (double)NTOK - 1.0 / 64.0;
  double sq = d * d;
#pragma unroll
  for (int off = 32; off > 0; off >>= 1) sq += __shfl_down(sq, off);
  if (e == 0) *out_loss = (float)(0.01 * sq);
}

extern "C" void kernel_launch(void* const* d_in, const int* in_sizes, int n_in,
                              void* d_out, int out_size, void* d_ws, size_t ws_size,
                              hipStream_t stream) {
  const float* x = (const float*)d_in[0];  // [16384][4096] fp32
  const float* W = (const float*)d_in[1];  // [64][4096] fp32

  float* out = (float*)d_out;
  float* scores = out;                    // [16384][8]
  float* idxf = out + (size_t)NTOK * 8;   // [16384][8]
  float* loss = out + (size_t)NTOK * 16;  // scalar

  // ws: [0,256) counts; g1/g2 fp16 [64][4096] each; part fp32 [4 splits][2 cls][16384][64]
  unsigned int* counts = (unsigned int*)d_ws;
  _Float16* g1 = (_Float16*)((char*)d_ws + 256);
  _Float16* g2 = g1 + (size_t)NEXP * HDIM;
  float* part = (float*)((char*)d_ws + 256 + (size_t)2 * NEXP * HDIM * sizeof(_Float16));

  hipMemsetAsync(d_ws, 0, 256, stream);
  wsplit_kernel<<<(NEXP * HDIM) / (256 * 4), 256, 0, stream>>>(W, g1, g2);
  gemm_mfma<<<(NTOK / TOKTILE) * SPLITS, 256, 0, stream>>>(x, g1, g2, part);
  topk_kernel<<<NTOK / 16, 1024, 0, stream>>>(part, scores, idxf, counts);
  loss_kernel<<<1, 64, 0, stream>>>(counts, loss);
}